// Round 1
// baseline (908.069 us; speedup 1.0000x reference)
//
#include <hip/hip_runtime.h>

static const int NN = 8000;    // nodes per graph (M == D)
static const int NE = 256000;  // edges per graph
static const int FF = 512;     // feature dim

// ---------------- graph preprocessing ----------------

__global__ __launch_bounds__(256) void k_init(float* deg, int* cnt, int n) {
  int i = blockIdx.x * 256 + threadIdx.x;
  if (i < n) { deg[i] = 1.0f; cnt[i] = 0; }
}

__global__ __launch_bounds__(256) void k_edge_w(const float* __restrict__ data,
                                                const int* __restrict__ ei,
                                                float* __restrict__ wbuf,
                                                float* __restrict__ deg,
                                                int* __restrict__ cnt,
                                                int E, int n) {
  int e = blockIdx.x * 256 + threadIdx.x;
  if (e >= E) return;
  int r = ei[e];
  int c = ei[E + e];
  float w = fmaxf(data[(size_t)r * n + c], 0.0f);
  wbuf[e] = w;
  atomicAdd(&deg[c], w);
  atomicAdd(&cnt[c], 1);
}

__global__ __launch_bounds__(256) void k_dinv(const float* __restrict__ deg,
                                              float* __restrict__ dinv, int n) {
  int i = blockIdx.x * 256 + threadIdx.x;
  if (i < n) dinv[i] = 1.0f / sqrtf(deg[i]);  // deg >= 1 always (self-loop)
}

// single block, 256 threads: exclusive scan of cnt[0..n) -> colptr; zero cnt
__global__ __launch_bounds__(256) void k_scan(const int* __restrict__ cnt,
                                              int* __restrict__ colptr,
                                              int* __restrict__ cntz, int n) {
  __shared__ int part[256];
  int t = threadIdx.x;
  const int CH = 32;  // 256*32 = 8192 >= n
  int base = t * CH;
  int local[CH];
  int s = 0;
  for (int i = 0; i < CH; ++i) {
    int idx = base + i;
    int v = (idx < n) ? cnt[idx] : 0;
    local[i] = s;
    s += v;
  }
  part[t] = s;
  __syncthreads();
  for (int o = 1; o < 256; o <<= 1) {
    int v = (t >= o) ? part[t - o] : 0;
    __syncthreads();
    part[t] += v;
    __syncthreads();
  }
  int pre = (t == 0) ? 0 : part[t - 1];
  for (int i = 0; i < CH; ++i) {
    int idx = base + i;
    if (idx < n) { colptr[idx] = pre + local[i]; cntz[idx] = 0; }
  }
  if (t == 255) colptr[n] = part[255];
}

__global__ __launch_bounds__(256) void k_scatter(const int* __restrict__ ei,
                                                 const float* __restrict__ wbuf,
                                                 const float* __restrict__ dinv,
                                                 const int* __restrict__ colptr,
                                                 int* __restrict__ cur,
                                                 int* __restrict__ srcs,
                                                 float* __restrict__ normv, int E) {
  int e = blockIdx.x * 256 + threadIdx.x;
  if (e >= E) return;
  int r = ei[e], c = ei[E + e];
  int pos = colptr[c] + atomicAdd(&cur[c], 1);
  srcs[pos] = r;
  normv[pos] = dinv[r] * wbuf[e] * dinv[c];
}

// ---------------- fp32 tiled GEMM: C[M x N] = A[M x K] @ B[K x N] ----------------
// grid = (M/64, N/64), block = 256, each thread 4x4. M%64==0, N%64==0, K%16==0.

template <bool BIAS, bool RELU>
__global__ __launch_bounds__(256) void k_gemm(const float* __restrict__ A,
                                              const float* __restrict__ B,
                                              const float* __restrict__ bias,
                                              float* __restrict__ C, int K, int N) {
  __shared__ __align__(16) float As[16][68];  // [k][m], pad 68: 2-way max
  __shared__ __align__(16) float Bs[16][68];  // [k][n]
  int tid = threadIdx.x;
  int m0 = blockIdx.x * 64, n0 = blockIdx.y * 64;
  int ak = tid & 15, am = tid >> 4;
  int bn = tid & 63, bk = tid >> 6;
  int tm = (tid >> 4) << 2, tn = (tid & 15) << 2;
  float acc[4][4];
#pragma unroll
  for (int i = 0; i < 4; ++i)
#pragma unroll
    for (int j = 0; j < 4; ++j) acc[i][j] = 0.0f;

  for (int k0 = 0; k0 < K; k0 += 16) {
#pragma unroll
    for (int p = 0; p < 4; ++p)
      As[ak][am + (p << 4)] = A[(size_t)(m0 + am + (p << 4)) * K + k0 + ak];
#pragma unroll
    for (int p = 0; p < 4; ++p)
      Bs[bk + (p << 2)][bn] = B[(size_t)(k0 + bk + (p << 2)) * N + n0 + bn];
    __syncthreads();
#pragma unroll
    for (int kk = 0; kk < 16; ++kk) {
      float4 a4 = *(const float4*)&As[kk][tm];
      float4 b4 = *(const float4*)&Bs[kk][tn];
      float a[4] = {a4.x, a4.y, a4.z, a4.w};
      float b[4] = {b4.x, b4.y, b4.z, b4.w};
#pragma unroll
      for (int i = 0; i < 4; ++i)
#pragma unroll
        for (int j = 0; j < 4; ++j) acc[i][j] = fmaf(a[i], b[j], acc[i][j]);
    }
    __syncthreads();
  }
#pragma unroll
  for (int i = 0; i < 4; ++i) {
    float o[4];
#pragma unroll
    for (int j = 0; j < 4; ++j) {
      float v = acc[i][j];
      if (BIAS) v += bias[n0 + tn + j];
      if (RELU) v = fmaxf(v, 0.0f);
      o[j] = v;
    }
    float4 o4 = {o[0], o[1], o[2], o[3]};
    *(float4*)&C[(size_t)(m0 + tm + i) * N + n0 + tn] = o4;
  }
}

// ---------------- sparse aggregation: out[c] = relu(sum norm*XW[src] + dinv^2*XW[c] + b) ----
// grid = NN, block = 128 (128 * float4 = 512 features)

__global__ __launch_bounds__(128) void k_aggregate(const float* __restrict__ XW,
                                                   const int* __restrict__ colptr,
                                                   const int* __restrict__ srcs,
                                                   const float* __restrict__ normv,
                                                   const float* __restrict__ dinv,
                                                   const float* __restrict__ bias,
                                                   float* __restrict__ out) {
  int c = blockIdx.x;
  int t = threadIdx.x;
  int e0 = colptr[c], e1 = colptr[c + 1];
  float di = dinv[c];
  float sl = di * di;  // self-loop norm
  float4 v = ((const float4*)(XW + (size_t)c * FF))[t];
  float ax = v.x * sl, ay = v.y * sl, az = v.z * sl, aw = v.w * sl;
  for (int e = e0; e < e1; ++e) {
    int s = srcs[e];
    float w = normv[e];
    float4 u = ((const float4*)(XW + (size_t)s * FF))[t];
    ax = fmaf(w, u.x, ax);
    ay = fmaf(w, u.y, ay);
    az = fmaf(w, u.z, az);
    aw = fmaf(w, u.w, aw);
  }
  float4 b4 = ((const float4*)bias)[t];
  float4 r;
  r.x = fmaxf(ax + b4.x, 0.0f);
  r.y = fmaxf(ay + b4.y, 0.0f);
  r.z = fmaxf(az + b4.z, 0.0f);
  r.w = fmaxf(aw + b4.w, 0.0f);
  ((float4*)(out + (size_t)c * FF))[t] = r;
}

// ---------------- final scores: C[NN x NN] = X[NN x 64] @ Y[NN x 64]^T ----------------
// grid = (125,125), block = 256, 64x64 tile, k-rotation swizzle for conflict-free b128.

__global__ __launch_bounds__(256) void k_score(const float* __restrict__ X,
                                               const float* __restrict__ Y,
                                               float* __restrict__ C) {
  __shared__ __align__(16) float Xs[64][64];
  __shared__ __align__(16) float Ys[64][64];
  int tid = threadIdx.x;
  int m0 = blockIdx.x * 64, n0 = blockIdx.y * 64;
  int kk = tid & 63, rr = tid >> 6;
#pragma unroll
  for (int p = 0; p < 16; ++p) {
    int r = rr + (p << 2);
    int kd = (kk + ((r >> 2) << 2)) & 63;  // rotate k by 4*(row/4)
    Xs[r][kd] = X[(size_t)(m0 + r) * 64 + kk];
    Ys[r][kd] = Y[(size_t)(n0 + r) * 64 + kk];
  }
  __syncthreads();
  int tm = (tid >> 4) << 2, tn = (tid & 15) << 2;
  float acc[4][4];
#pragma unroll
  for (int i = 0; i < 4; ++i)
#pragma unroll
    for (int j = 0; j < 4; ++j) acc[i][j] = 0.0f;
#pragma unroll
  for (int k0 = 0; k0 < 64; k0 += 4) {
    float4 xa[4], yb[4];
#pragma unroll
    for (int i = 0; i < 4; ++i) {
      int rm = tm + i;
      xa[i] = *(const float4*)&Xs[rm][(k0 + ((rm >> 2) << 2)) & 63];
      int rn = tn + i;
      yb[i] = *(const float4*)&Ys[rn][(k0 + ((rn >> 2) << 2)) & 63];
    }
#pragma unroll
    for (int i = 0; i < 4; ++i)
#pragma unroll
      for (int j = 0; j < 4; ++j) {
        acc[i][j] = fmaf(xa[i].x, yb[j].x, acc[i][j]);
        acc[i][j] = fmaf(xa[i].y, yb[j].y, acc[i][j]);
        acc[i][j] = fmaf(xa[i].z, yb[j].z, acc[i][j]);
        acc[i][j] = fmaf(xa[i].w, yb[j].w, acc[i][j]);
      }
  }
#pragma unroll
  for (int i = 0; i < 4; ++i) {
    float4 o = {acc[i][0], acc[i][1], acc[i][2], acc[i][3]};
    *(float4*)&C[(size_t)(m0 + tm + i) * NN + n0 + tn] = o;
  }
}

// ---------------- host orchestration ----------------

static void run_graph(const float* x, const float* data, const int* ei,
                      const float* W1, const float* b1,
                      const float* W2, const float* b2,
                      const float* l1w, const float* l1b,
                      const float* l2w, const float* l2b,
                      const float* l3w, const float* l3b,
                      float* fin, float* bufA, float* bufB,
                      float* wbuf, float* normv, int* srcs,
                      float* deg, float* dinv, int* cnt, int* colptr,
                      hipStream_t stream) {
  int nb = (NN + 255) / 256;
  int eb = (NE + 255) / 256;
  k_init<<<nb, 256, 0, stream>>>(deg, cnt, NN);
  k_edge_w<<<eb, 256, 0, stream>>>(data, ei, wbuf, deg, cnt, NE, NN);
  k_dinv<<<nb, 256, 0, stream>>>(deg, dinv, NN);
  k_scan<<<1, 256, 0, stream>>>(cnt, colptr, cnt, NN);
  k_scatter<<<eb, 256, 0, stream>>>(ei, wbuf, dinv, colptr, cnt, srcs, normv, NE);
  // GCN layer 1: XW = x @ W1 ; H1 = relu(agg(XW) + b1)
  k_gemm<false, false><<<dim3(NN / 64, FF / 64), 256, 0, stream>>>(x, W1, nullptr, bufA, FF, FF);
  k_aggregate<<<NN, 128, 0, stream>>>(bufA, colptr, srcs, normv, dinv, b1, bufB);
  // GCN layer 2
  k_gemm<false, false><<<dim3(NN / 64, FF / 64), 256, 0, stream>>>(bufB, W2, nullptr, bufA, FF, FF);
  k_aggregate<<<NN, 128, 0, stream>>>(bufA, colptr, srcs, normv, dinv, b2, bufB);
  // MLP: 512 -> 256 -> 128 -> 64, relu each
  k_gemm<true, true><<<dim3(NN / 64, 256 / 64), 256, 0, stream>>>(bufB, l1w, l1b, bufA, 512, 256);
  k_gemm<true, true><<<dim3(NN / 64, 128 / 64), 256, 0, stream>>>(bufA, l2w, l2b, bufB, 256, 128);
  k_gemm<true, true><<<dim3(NN / 64, 64 / 64), 256, 0, stream>>>(bufB, l3w, l3b, fin, 128, 64);
}

extern "C" void kernel_launch(void* const* d_in, const int* in_sizes, int n_in,
                              void* d_out, int out_size, void* d_ws, size_t ws_size,
                              hipStream_t stream) {
  const float* x_m    = (const float*)d_in[0];
  const float* x_d    = (const float*)d_in[1];
  const float* data_m = (const float*)d_in[2];
  const float* data_d = (const float*)d_in[3];
  const int*   ei_m   = (const int*)d_in[4];
  const int*   ei_d   = (const int*)d_in[5];
  const float* Wg1 = (const float*)d_in[6];
  const float* bg1 = (const float*)d_in[7];
  const float* Wg2 = (const float*)d_in[8];
  const float* bg2 = (const float*)d_in[9];
  const float* Wd1 = (const float*)d_in[10];
  const float* bd1 = (const float*)d_in[11];
  const float* Wd2 = (const float*)d_in[12];
  const float* bd2 = (const float*)d_in[13];
  const float* lx1_w = (const float*)d_in[14];
  const float* lx1_b = (const float*)d_in[15];
  const float* lx2_w = (const float*)d_in[16];
  const float* lx2_b = (const float*)d_in[17];
  const float* lx3_w = (const float*)d_in[18];
  const float* lx3_b = (const float*)d_in[19];
  const float* ly1_w = (const float*)d_in[20];
  const float* ly1_b = (const float*)d_in[21];
  const float* ly2_w = (const float*)d_in[22];
  const float* ly2_b = (const float*)d_in[23];
  const float* ly3_w = (const float*)d_in[24];
  const float* ly3_b = (const float*)d_in[25];
  float* out = (float*)d_out;

  char* base = (char*)d_ws;
  size_t off = 0;
  auto alloc = [&](size_t bytes) -> char* {
    char* p = base + off;
    off += (bytes + 255) & ~(size_t)255;
    return p;
  };
  float* bufA   = (float*)alloc((size_t)NN * FF * 4);   // 16.4 MB
  float* bufB   = (float*)alloc((size_t)NN * FF * 4);   // 16.4 MB
  float* xfin   = (float*)alloc((size_t)NN * 64 * 4);   // 2 MB
  float* yfin   = (float*)alloc((size_t)NN * 64 * 4);   // 2 MB
  float* wbuf   = (float*)alloc((size_t)NE * 4);
  float* normv  = (float*)alloc((size_t)NE * 4);
  int*   srcs   = (int*)alloc((size_t)NE * 4);
  float* deg    = (float*)alloc((size_t)NN * 4);
  float* dinv   = (float*)alloc((size_t)NN * 4);
  int*   cnt    = (int*)alloc((size_t)NN * 4);
  int*   colptr = (int*)alloc((size_t)(NN + 1) * 4);

  run_graph(x_m, data_m, ei_m, Wg1, bg1, Wg2, bg2,
            lx1_w, lx1_b, lx2_w, lx2_b, lx3_w, lx3_b,
            xfin, bufA, bufB, wbuf, normv, srcs, deg, dinv, cnt, colptr, stream);
  run_graph(x_d, data_d, ei_d, Wd1, bd1, Wd2, bd2,
            ly1_w, ly1_b, ly2_w, ly2_b, ly3_w, ly3_b,
            yfin, bufA, bufB, wbuf, normv, srcs, deg, dinv, cnt, colptr, stream);

  k_score<<<dim3(NN / 64, NN / 64), 256, 0, stream>>>(xfin, yfin, out);
}

// Round 2
// 717.151 us; speedup vs baseline: 1.2662x; 1.2662x over previous
//
#include <hip/hip_runtime.h>

typedef unsigned short u16;
typedef unsigned int u32;
typedef __attribute__((ext_vector_type(8))) short bf16x8;
typedef __attribute__((ext_vector_type(4))) float f32x4;
typedef __attribute__((ext_vector_type(4))) unsigned short u16x4;

static const int NN = 8000;    // nodes per graph (M == D)
static const int NE = 256000;  // edges per graph
static const int FF = 512;     // feature dim
static const int MP = 8064;    // 63 * 128 padded rows

__device__ __forceinline__ u16 f2bf(float x) {
  union { float f; u32 u; } a; a.f = x;
  u32 r = a.u + 0x7FFF + ((a.u >> 16) & 1);  // RNE
  return (u16)(r >> 16);
}
__device__ __forceinline__ float bf2f(u16 b) {
  union { float f; u32 u; } a; a.u = ((u32)b) << 16;
  return a.f;
}

__device__ __forceinline__ void gload_lds16(const void* g, void* l) {
  __builtin_amdgcn_global_load_lds(
      (const __attribute__((address_space(1))) unsigned int*)g,
      (__attribute__((address_space(3))) unsigned int*)l, 16, 0, 0);
}

// ---------------- graph preprocessing ----------------

__global__ __launch_bounds__(256) void k_init(float* deg, int* cnt, int n) {
  int i = blockIdx.x * 256 + threadIdx.x;
  if (i < n) { deg[i] = 1.0f; cnt[i] = 0; }
}

__global__ __launch_bounds__(256) void k_edge_w(const float* __restrict__ data,
                                                const int* __restrict__ ei,
                                                float* __restrict__ wbuf,
                                                float* __restrict__ deg,
                                                int* __restrict__ cnt,
                                                int E, int n) {
  int e = blockIdx.x * 256 + threadIdx.x;
  if (e >= E) return;
  int r = ei[e];
  int c = ei[E + e];
  float w = fmaxf(data[(size_t)r * n + c], 0.0f);
  wbuf[e] = w;
  atomicAdd(&deg[c], w);
  atomicAdd(&cnt[c], 1);
}

__global__ __launch_bounds__(256) void k_dinv(const float* __restrict__ deg,
                                              float* __restrict__ dinv, int n) {
  int i = blockIdx.x * 256 + threadIdx.x;
  if (i < n) dinv[i] = 1.0f / sqrtf(deg[i]);
}

__global__ __launch_bounds__(256) void k_scan(const int* __restrict__ cnt,
                                              int* __restrict__ colptr,
                                              int* __restrict__ cntz, int n) {
  __shared__ int part[256];
  int t = threadIdx.x;
  const int CH = 32;
  int base = t * CH;
  int local[CH];
  int s = 0;
  for (int i = 0; i < CH; ++i) {
    int idx = base + i;
    int v = (idx < n) ? cnt[idx] : 0;
    local[i] = s;
    s += v;
  }
  part[t] = s;
  __syncthreads();
  for (int o = 1; o < 256; o <<= 1) {
    int v = (t >= o) ? part[t - o] : 0;
    __syncthreads();
    part[t] += v;
    __syncthreads();
  }
  int pre = (t == 0) ? 0 : part[t - 1];
  for (int i = 0; i < CH; ++i) {
    int idx = base + i;
    if (idx < n) { colptr[idx] = pre + local[i]; cntz[idx] = 0; }
  }
  if (t == 255) colptr[n] = part[255];
}

__global__ __launch_bounds__(256) void k_scatter(const int* __restrict__ ei,
                                                 const float* __restrict__ wbuf,
                                                 const float* __restrict__ dinv,
                                                 const int* __restrict__ colptr,
                                                 int* __restrict__ cur,
                                                 int* __restrict__ srcs,
                                                 float* __restrict__ normv, int E) {
  int e = blockIdx.x * 256 + threadIdx.x;
  if (e >= E) return;
  int r = ei[e], c = ei[E + e];
  int pos = colptr[c] + atomicAdd(&cur[c], 1);
  srcs[pos] = r;
  normv[pos] = dinv[r] * wbuf[e] * dinv[c];
}

// ---------------- fp32 -> bf16 hi/lo split helpers ----------------

// activation split, row-padded with zeros: in [M][F] -> planes [Mp][F]
__global__ __launch_bounds__(256) void k_split_act(const float* __restrict__ in,
                                                   u16* __restrict__ ph,
                                                   u16* __restrict__ pl,
                                                   int tot_in, int tot_pad) {
  int i = (blockIdx.x * 256 + threadIdx.x) * 4;
  if (i >= tot_pad) return;
  float4 v = (i < tot_in) ? *(const float4*)&in[i] : make_float4(0.f, 0.f, 0.f, 0.f);
  u16x4 h, l;
#pragma unroll
  for (int e = 0; e < 4; ++e) {
    float x = (&v.x)[e];
    u16 hh = f2bf(x);
    h[e] = hh;
    l[e] = f2bf(x - bf2f(hh));
  }
  *(u16x4*)&ph[i] = h;
  *(u16x4*)&pl[i] = l;
}

// weight transpose + split: W [K][N] -> Th/Tl [N][K]
__global__ __launch_bounds__(256) void k_split_wT(const float* __restrict__ W,
                                                  u16* __restrict__ Th,
                                                  u16* __restrict__ Tl,
                                                  int K, int N) {
  __shared__ float tile[32][33];
  int tx = threadIdx.x & 31, ty = threadIdx.x >> 5;  // ty 0..7
  int n0 = blockIdx.x * 32, k0 = blockIdx.y * 32;
#pragma unroll
  for (int r = 0; r < 32; r += 8)
    tile[r + ty][tx] = W[(size_t)(k0 + r + ty) * N + n0 + tx];
  __syncthreads();
#pragma unroll
  for (int r = 0; r < 32; r += 8) {
    float v = tile[tx][r + ty];  // = W[k0+tx][n0+r+ty]
    int n = n0 + r + ty, k = k0 + tx;
    u16 h = f2bf(v);
    Th[(size_t)n * K + k] = h;
    Tl[(size_t)n * K + k] = f2bf(v - bf2f(h));
  }
}

// ---------------- bf16x3 MFMA GEMM ----------------
// C[M x N] = A[M x K] @ B[K x N], A given as hi/lo planes [Mp][K], B given
// TRANSPOSED as hi/lo planes [Np][K]. Tile 128x128, BK=32, 4 waves (2x2),
// per-wave 64x64 = 4x4 fragments of 16x16x32 bf16 MFMA, 3 MFMA per fragment
// (hi*hi + lo*hi + hi*lo). Double-buffered LDS, global_load_lds staging with
// chunk-XOR swizzle c ^= (row>>2)&3 applied on both source and read side.

template <bool BIAS, bool RELU, bool NGUARD>
__global__ __launch_bounds__(256) void k_mm(const u16* __restrict__ Ah,
                                            const u16* __restrict__ Al,
                                            const u16* __restrict__ Bh,
                                            const u16* __restrict__ Bl,
                                            const float* __restrict__ bias,
                                            float* __restrict__ C,
                                            int M, int N, int K) {
  __shared__ __align__(16) u16 lds[2][4][4096];  // [dbuf][Ah,Al,Bh,Bl][128*32]
  int tid = threadIdx.x;
  int wv = tid >> 6, ln = tid & 63;
  int l15 = ln & 15, l4 = ln >> 4;
  int m0 = blockIdx.x * 128, n0 = blockIdx.y * 128;
  int wm = (wv & 1) * 64, wn = (wv >> 1) * 64;
  const u16* gb = (wv == 0) ? Ah : (wv == 1) ? Al : (wv == 2) ? Bh : Bl;
  int row0 = (wv < 2) ? m0 : n0;

  f32x4 acc[4][4];
  f32x4 zz = {0.f, 0.f, 0.f, 0.f};
#pragma unroll
  for (int i = 0; i < 4; ++i)
#pragma unroll
    for (int j = 0; j < 4; ++j) acc[i][j] = zz;

  auto stage = [&](int d, int k0) {
#pragma unroll
    for (int it = 0; it < 8; ++it) {
      int slot = it * 64 + ln;
      int r = slot >> 2, c = slot & 3;
      int gc = c ^ ((r >> 2) & 3);
      gload_lds16(gb + ((size_t)(row0 + r) * K + k0 + gc * 8),
                  &lds[d][wv][it * 512]);
    }
  };

  auto compute = [&](int d) {
    bf16x8 ah[4], al[4], bh[4], bl[4];
#pragma unroll
    for (int i = 0; i < 4; ++i) {
      int r = wm + i * 16 + l15;
      int off = r * 32 + ((l4 ^ ((r >> 2) & 3)) << 3);
      ah[i] = *(const bf16x8*)&lds[d][0][off];
      al[i] = *(const bf16x8*)&lds[d][1][off];
    }
#pragma unroll
    for (int j = 0; j < 4; ++j) {
      int r = wn + j * 16 + l15;
      int off = r * 32 + ((l4 ^ ((r >> 2) & 3)) << 3);
      bh[j] = *(const bf16x8*)&lds[d][2][off];
      bl[j] = *(const bf16x8*)&lds[d][3][off];
    }
#pragma unroll
    for (int i = 0; i < 4; ++i)
#pragma unroll
      for (int j = 0; j < 4; ++j) {
        acc[i][j] = __builtin_amdgcn_mfma_f32_16x16x32_bf16(ah[i], bh[j], acc[i][j], 0, 0, 0);
        acc[i][j] = __builtin_amdgcn_mfma_f32_16x16x32_bf16(al[i], bh[j], acc[i][j], 0, 0, 0);
        acc[i][j] = __builtin_amdgcn_mfma_f32_16x16x32_bf16(ah[i], bl[j], acc[i][j], 0, 0, 0);
      }
  };

  stage(0, 0);
  __syncthreads();
  int nk = K >> 5;
  for (int t = 0; t < nk; ++t) {
    int cur = t & 1;
    if (t + 1 < nk) stage(cur ^ 1, (t + 1) << 5);
    compute(cur);
    __syncthreads();
  }

  // epilogue: D layout col = lane&15, row = 4*(lane>>4) + reg
  int mb = m0 + wm + l4 * 4;
  int nb = n0 + wn + l15;
#pragma unroll
  for (int j = 0; j < 4; ++j) {
    int n = nb + j * 16;
    if (NGUARD && n >= N) continue;
    float bj = BIAS ? bias[n] : 0.0f;
#pragma unroll
    for (int i = 0; i < 4; ++i) {
#pragma unroll
      for (int rr = 0; rr < 4; ++rr) {
        int m = mb + i * 16 + rr;
        if (m < M) {
          float v = acc[i][j][rr] + bj;
          if (RELU) v = fmaxf(v, 0.0f);
          C[(size_t)m * N + n] = v;
        }
      }
    }
  }
}

// ---------------- fp32 tiled GEMM (small MLP tail layers) ----------------

template <bool BIAS, bool RELU>
__global__ __launch_bounds__(256) void k_gemm(const float* __restrict__ A,
                                              const float* __restrict__ B,
                                              const float* __restrict__ bias,
                                              float* __restrict__ C, int K, int N) {
  __shared__ __align__(16) float As[16][68];
  __shared__ __align__(16) float Bs[16][68];
  int tid = threadIdx.x;
  int m0 = blockIdx.x * 64, n0 = blockIdx.y * 64;
  int ak = tid & 15, am = tid >> 4;
  int bn = tid & 63, bk = tid >> 6;
  int tm = (tid >> 4) << 2, tn = (tid & 15) << 2;
  float acc[4][4];
#pragma unroll
  for (int i = 0; i < 4; ++i)
#pragma unroll
    for (int j = 0; j < 4; ++j) acc[i][j] = 0.0f;

  for (int k0 = 0; k0 < K; k0 += 16) {
#pragma unroll
    for (int p = 0; p < 4; ++p)
      As[ak][am + (p << 4)] = A[(size_t)(m0 + am + (p << 4)) * K + k0 + ak];
#pragma unroll
    for (int p = 0; p < 4; ++p)
      Bs[bk + (p << 2)][bn] = B[(size_t)(k0 + bk + (p << 2)) * N + n0 + bn];
    __syncthreads();
#pragma unroll
    for (int kk = 0; kk < 16; ++kk) {
      float4 a4 = *(const float4*)&As[kk][tm];
      float4 b4 = *(const float4*)&Bs[kk][tn];
      float a[4] = {a4.x, a4.y, a4.z, a4.w};
      float b[4] = {b4.x, b4.y, b4.z, b4.w};
#pragma unroll
      for (int i = 0; i < 4; ++i)
#pragma unroll
        for (int j = 0; j < 4; ++j) acc[i][j] = fmaf(a[i], b[j], acc[i][j]);
    }
    __syncthreads();
  }
#pragma unroll
  for (int i = 0; i < 4; ++i) {
    float o[4];
#pragma unroll
    for (int j = 0; j < 4; ++j) {
      float v = acc[i][j];
      if (BIAS) v += bias[n0 + tn + j];
      if (RELU) v = fmaxf(v, 0.0f);
      o[j] = v;
    }
    float4 o4 = {o[0], o[1], o[2], o[3]};
    *(float4*)&C[(size_t)(m0 + tm + i) * N + n0 + tn] = o4;
  }
}

// ---------------- sparse aggregation -> bf16 hi/lo planes ----------------
// out[c] = relu(sum norm*XW[src] + dinv^2*XW[c] + b); write hi/lo planes [Mp][FF]

__global__ __launch_bounds__(128) void k_aggregate(const float* __restrict__ XW,
                                                   const int* __restrict__ colptr,
                                                   const int* __restrict__ srcs,
                                                   const float* __restrict__ normv,
                                                   const float* __restrict__ dinv,
                                                   const float* __restrict__ bias,
                                                   u16* __restrict__ Hh,
                                                   u16* __restrict__ Hl) {
  int c = blockIdx.x;
  int t = threadIdx.x;
  int e0 = colptr[c], e1 = colptr[c + 1];
  float di = dinv[c];
  float sl = di * di;
  float4 v = ((const float4*)(XW + (size_t)c * FF))[t];
  float ax = v.x * sl, ay = v.y * sl, az = v.z * sl, aw = v.w * sl;
  for (int e = e0; e < e1; ++e) {
    int s = srcs[e];
    float w = normv[e];
    float4 u = ((const float4*)(XW + (size_t)s * FF))[t];
    ax = fmaf(w, u.x, ax);
    ay = fmaf(w, u.y, ay);
    az = fmaf(w, u.z, az);
    aw = fmaf(w, u.w, aw);
  }
  float4 b4 = ((const float4*)bias)[t];
  float o[4];
  o[0] = fmaxf(ax + b4.x, 0.0f);
  o[1] = fmaxf(ay + b4.y, 0.0f);
  o[2] = fmaxf(az + b4.z, 0.0f);
  o[3] = fmaxf(aw + b4.w, 0.0f);
  u16x4 hh, ll;
#pragma unroll
  for (int e = 0; e < 4; ++e) {
    u16 h = f2bf(o[e]);
    hh[e] = h;
    ll[e] = f2bf(o[e] - bf2f(h));
  }
  *(u16x4*)&Hh[(size_t)c * FF + 4 * t] = hh;
  *(u16x4*)&Hl[(size_t)c * FF + 4 * t] = ll;
}

// ---------------- host orchestration ----------------

static void run_graph(const float* x, const float* data, const int* ei,
                      const float* W1, const float* b1,
                      const float* W2, const float* b2,
                      const float* l1w, const float* l1b,
                      const float* l2w, const float* l2b,
                      const float* l3w, const float* l3b,
                      u16* finh, u16* finl,
                      u16* xh, u16* xl, u16* hh, u16* hl,
                      u16* wth, u16* wtl,
                      float* bufA, float* bufB,
                      float* wbuf, float* normv, int* srcs,
                      float* deg, float* dinv, int* cnt, int* colptr,
                      hipStream_t stream) {
  int nb = (NN + 255) / 256;
  int eb = (NE + 255) / 256;
  k_init<<<nb, 256, 0, stream>>>(deg, cnt, NN);
  k_edge_w<<<eb, 256, 0, stream>>>(data, ei, wbuf, deg, cnt, NE, NN);
  k_dinv<<<nb, 256, 0, stream>>>(deg, dinv, NN);
  k_scan<<<1, 256, 0, stream>>>(cnt, colptr, cnt, NN);
  k_scatter<<<eb, 256, 0, stream>>>(ei, wbuf, dinv, colptr, cnt, srcs, normv, NE);

  int sb = (MP * FF / 4 + 255) / 256;
  k_split_act<<<sb, 256, 0, stream>>>(x, xh, xl, NN * FF, MP * FF);

  // GCN layer 1: XW = x @ W1 (MFMA) ; H1 = relu(agg(XW)+b1) -> hi/lo planes
  k_split_wT<<<dim3(FF / 32, FF / 32), 256, 0, stream>>>(W1, wth, wtl, FF, FF);
  k_mm<false, false, false><<<dim3(63, FF / 128), 256, 0, stream>>>(
      xh, xl, wth, wtl, nullptr, bufA, NN, FF, FF);
  k_aggregate<<<NN, 128, 0, stream>>>(bufA, colptr, srcs, normv, dinv, b1, hh, hl);

  // GCN layer 2
  k_split_wT<<<dim3(FF / 32, FF / 32), 256, 0, stream>>>(W2, wth, wtl, FF, FF);
  k_mm<false, false, false><<<dim3(63, FF / 128), 256, 0, stream>>>(
      hh, hl, wth, wtl, nullptr, bufA, NN, FF, FF);
  k_aggregate<<<NN, 128, 0, stream>>>(bufA, colptr, srcs, normv, dinv, b2, hh, hl);

  // MLP1 (MFMA): [8000,512]@[512,256] + bias, relu -> bufB fp32
  k_split_wT<<<dim3(256 / 32, FF / 32), 256, 0, stream>>>(l1w, wth, wtl, FF, 256);
  k_mm<true, true, false><<<dim3(63, 256 / 128), 256, 0, stream>>>(
      hh, hl, wth, wtl, l1b, bufB, NN, 256, FF);

  // MLP2/3 fp32 (tiny)
  k_gemm<true, true><<<dim3(NN / 64, 128 / 64), 256, 0, stream>>>(bufB, l2w, l2b, bufA, 256, 128);
  k_gemm<true, true><<<dim3(NN / 64, 64 / 64), 256, 0, stream>>>(bufA, l3w, l3b, bufB, 128, 64);

  int fb = (MP * 64 / 4 + 255) / 256;
  k_split_act<<<fb, 256, 0, stream>>>(bufB, finh, finl, NN * 64, MP * 64);
}

extern "C" void kernel_launch(void* const* d_in, const int* in_sizes, int n_in,
                              void* d_out, int out_size, void* d_ws, size_t ws_size,
                              hipStream_t stream) {
  const float* x_m    = (const float*)d_in[0];
  const float* x_d    = (const float*)d_in[1];
  const float* data_m = (const float*)d_in[2];
  const float* data_d = (const float*)d_in[3];
  const int*   ei_m   = (const int*)d_in[4];
  const int*   ei_d   = (const int*)d_in[5];
  const float* Wg1 = (const float*)d_in[6];
  const float* bg1 = (const float*)d_in[7];
  const float* Wg2 = (const float*)d_in[8];
  const float* bg2 = (const float*)d_in[9];
  const float* Wd1 = (const float*)d_in[10];
  const float* bd1 = (const float*)d_in[11];
  const float* Wd2 = (const float*)d_in[12];
  const float* bd2 = (const float*)d_in[13];
  const float* lx1_w = (const float*)d_in[14];
  const float* lx1_b = (const float*)d_in[15];
  const float* lx2_w = (const float*)d_in[16];
  const float* lx2_b = (const float*)d_in[17];
  const float* lx3_w = (const float*)d_in[18];
  const float* lx3_b = (const float*)d_in[19];
  const float* ly1_w = (const float*)d_in[20];
  const float* ly1_b = (const float*)d_in[21];
  const float* ly2_w = (const float*)d_in[22];
  const float* ly2_b = (const float*)d_in[23];
  const float* ly3_w = (const float*)d_in[24];
  const float* ly3_b = (const float*)d_in[25];
  float* out = (float*)d_out;

  char* base = (char*)d_ws;
  size_t off = 0;
  auto alloc = [&](size_t bytes) -> char* {
    char* p = base + off;
    off += (bytes + 255) & ~(size_t)255;
    return p;
  };
  u16* xh = (u16*)alloc((size_t)MP * FF * 2);
  u16* xl = (u16*)alloc((size_t)MP * FF * 2);
  u16* hh = (u16*)alloc((size_t)MP * FF * 2);
  u16* hl = (u16*)alloc((size_t)MP * FF * 2);
  u16* wth = (u16*)alloc((size_t)FF * FF * 2);
  u16* wtl = (u16*)alloc((size_t)FF * FF * 2);
  float* bufA = (float*)alloc((size_t)NN * FF * 4);
  float* bufB = (float*)alloc((size_t)NN * 256 * 4);
  u16* fxh = (u16*)alloc((size_t)MP * 64 * 2);
  u16* fxl = (u16*)alloc((size_t)MP * 64 * 2);
  u16* fyh = (u16*)alloc((size_t)MP * 64 * 2);
  u16* fyl = (u16*)alloc((size_t)MP * 64 * 2);
  float* wbuf   = (float*)alloc((size_t)NE * 4);
  float* normv  = (float*)alloc((size_t)NE * 4);
  int*   srcs   = (int*)alloc((size_t)NE * 4);
  float* deg    = (float*)alloc((size_t)NN * 4);
  float* dinv   = (float*)alloc((size_t)NN * 4);
  int*   cnt    = (int*)alloc((size_t)NN * 4);
  int*   colptr = (int*)alloc((size_t)(NN + 1) * 4);

  run_graph(x_m, data_m, ei_m, Wg1, bg1, Wg2, bg2,
            lx1_w, lx1_b, lx2_w, lx2_b, lx3_w, lx3_b,
            fxh, fxl, xh, xl, hh, hl, wth, wtl, bufA, bufB,
            wbuf, normv, srcs, deg, dinv, cnt, colptr, stream);
  run_graph(x_d, data_d, ei_d, Wd1, bd1, Wd2, bd2,
            ly1_w, ly1_b, ly2_w, ly2_b, ly3_w, ly3_b,
            fyh, fyl, xh, xl, hh, hl, wth, wtl, bufA, bufB,
            wbuf, normv, srcs, deg, dinv, cnt, colptr, stream);

  // scores = x @ y^T : A planes [MP][64], B planes [MP][64], N-guarded
  k_mm<false, false, true><<<dim3(63, 63), 256, 0, stream>>>(
      fxh, fxl, fyh, fyl, nullptr, out, NN, NN, 64);
}

// Round 3
// 578.439 us; speedup vs baseline: 1.5699x; 1.2398x over previous
//
#include <hip/hip_runtime.h>

typedef unsigned short u16;
typedef unsigned int u32;
typedef __attribute__((ext_vector_type(8))) short bf16x8;
typedef __attribute__((ext_vector_type(4))) float f32x4;
typedef __attribute__((ext_vector_type(4))) unsigned short u16x4;

static const int NN = 8000;    // nodes per graph (M == D)
static const int NE = 256000;  // edges per graph
static const int FF = 512;     // feature dim
static const int MP = 8064;    // 63 * 128 padded rows

__device__ __forceinline__ u16 f2bf(float x) {
  union { float f; u32 u; } a; a.f = x;
  u32 r = a.u + 0x7FFF + ((a.u >> 16) & 1);  // RNE
  return (u16)(r >> 16);
}
__device__ __forceinline__ float bf2f(u16 b) {
  union { float f; u32 u; } a; a.u = ((u32)b) << 16;
  return a.f;
}

__device__ __forceinline__ void gload_lds16(const void* g, void* l) {
  __builtin_amdgcn_global_load_lds(
      (const __attribute__((address_space(1))) unsigned int*)g,
      (__attribute__((address_space(3))) unsigned int*)l, 16, 0, 0);
}

// ---------------- batched arg structs (blockIdx.z = graph) ----------------

struct PreArgs {
  const float* data[2];
  const int* ei[2];
  float* wbuf[2];
  float* deg[2];
  int* cnt[2];
  float* dinv[2];
  int* colptr[2];
  int* srcs[2];
  float* normv[2];
};

struct SplitArgs {
  const float* x[2];
  u16* ph[2];
  u16* pl[2];
};

struct WTArgs {
  const float* W[2];
  u16* Th[2];
  u16* Tl[2];
};

struct MMArgs {
  const u16* Ah[2]; const u16* Al[2];
  const u16* Bh[2]; const u16* Bl[2];
  const float* bias[2];
  float* C[2];          // fp32 output (when !OUTPLANES)
  u16* Ch[2]; u16* Cl[2];  // plane outputs (when OUTPLANES)
};

struct AggArgs {
  const float* XW[2];
  const int* colptr[2];
  const int* srcs[2];
  const float* normv[2];
  const float* dinv[2];
  const float* bias[2];
  u16* Hh[2];
  u16* Hl[2];
};

// ---------------- graph preprocessing ----------------

__global__ __launch_bounds__(256) void k_init(PreArgs p, int n) {
  int z = blockIdx.z;
  int i = blockIdx.x * 256 + threadIdx.x;
  if (i < n) { p.deg[z][i] = 1.0f; p.cnt[z][i] = 0; }
}

__global__ __launch_bounds__(256) void k_edge_w(PreArgs p, int E, int n) {
  int z = blockIdx.z;
  int e = blockIdx.x * 256 + threadIdx.x;
  if (e >= E) return;
  const int* ei = p.ei[z];
  int r = ei[e];
  int c = ei[E + e];
  float w = fmaxf(p.data[z][(size_t)r * n + c], 0.0f);
  p.wbuf[z][e] = w;
  atomicAdd(&p.deg[z][c], w);
  atomicAdd(&p.cnt[z][c], 1);
}

__global__ __launch_bounds__(256) void k_dinv(PreArgs p, int n) {
  int z = blockIdx.z;
  int i = blockIdx.x * 256 + threadIdx.x;
  if (i < n) p.dinv[z][i] = 1.0f / sqrtf(p.deg[z][i]);
}

// one block per z: exclusive scan of cnt -> colptr; zero cnt
__global__ __launch_bounds__(256) void k_scan(PreArgs p, int n) {
  int z = blockIdx.z;
  const int* cnt = p.cnt[z];
  int* colptr = p.colptr[z];
  int* cntz = p.cnt[z];
  __shared__ int part[256];
  int t = threadIdx.x;
  const int CH = 32;
  int base = t * CH;
  int local[CH];
  int s = 0;
  for (int i = 0; i < CH; ++i) {
    int idx = base + i;
    int v = (idx < n) ? cnt[idx] : 0;
    local[i] = s;
    s += v;
  }
  part[t] = s;
  __syncthreads();
  for (int o = 1; o < 256; o <<= 1) {
    int v = (t >= o) ? part[t - o] : 0;
    __syncthreads();
    part[t] += v;
    __syncthreads();
  }
  int pre = (t == 0) ? 0 : part[t - 1];
  for (int i = 0; i < CH; ++i) {
    int idx = base + i;
    if (idx < n) { colptr[idx] = pre + local[i]; cntz[idx] = 0; }
  }
  if (t == 255) colptr[n] = part[255];
}

__global__ __launch_bounds__(256) void k_scatter(PreArgs p, int E) {
  int z = blockIdx.z;
  int e = blockIdx.x * 256 + threadIdx.x;
  if (e >= E) return;
  const int* ei = p.ei[z];
  int r = ei[e], c = ei[E + e];
  int pos = p.colptr[z][c] + atomicAdd(&p.cnt[z][c], 1);
  p.srcs[z][pos] = r;
  p.normv[z][pos] = p.dinv[z][r] * p.wbuf[z][e] * p.dinv[z][c];
}

// ---------------- fp32 -> bf16 hi/lo split (activations, zero-padded) ------

__global__ __launch_bounds__(256) void k_split_act(SplitArgs a, int tot_in, int tot_pad) {
  int z = blockIdx.z;
  int i = (blockIdx.x * 256 + threadIdx.x) * 4;
  if (i >= tot_pad) return;
  float4 v = (i < tot_in) ? *(const float4*)&a.x[z][i] : make_float4(0.f, 0.f, 0.f, 0.f);
  u16x4 h, l;
#pragma unroll
  for (int e = 0; e < 4; ++e) {
    float x = (&v.x)[e];
    u16 hh = f2bf(x);
    h[e] = hh;
    l[e] = f2bf(x - bf2f(hh));
  }
  *(u16x4*)&a.ph[z][i] = h;
  *(u16x4*)&a.pl[z][i] = l;
}

// weight transpose + split: W [K][N] -> Th/Tl [N][K]
__global__ __launch_bounds__(256) void k_split_wT(WTArgs a, int K, int N) {
  int z = blockIdx.z;
  __shared__ float tile[32][33];
  int tx = threadIdx.x & 31, ty = threadIdx.x >> 5;
  int n0 = blockIdx.x * 32, k0 = blockIdx.y * 32;
#pragma unroll
  for (int r = 0; r < 32; r += 8)
    tile[r + ty][tx] = a.W[z][(size_t)(k0 + r + ty) * N + n0 + tx];
  __syncthreads();
#pragma unroll
  for (int r = 0; r < 32; r += 8) {
    float v = tile[tx][r + ty];
    int n = n0 + r + ty, k = k0 + tx;
    u16 h = f2bf(v);
    a.Th[z][(size_t)n * K + k] = h;
    a.Tl[z][(size_t)n * K + k] = f2bf(v - bf2f(h));
  }
}

// ---------------- bf16x3 MFMA GEMM ----------------
// C[M x N] = A[M x K] @ B[K x N]; A planes [Mp][K], B planes (transposed)
// [Np][K]. 128x128 tile, BK=32, 4 waves, double-buffered global_load_lds
// staging with chunk-XOR swizzle, 3 MFMA per fragment (hh + lh + hl).
// Epilogue: acc -> LDS f32 tile (stride 132) -> coalesced stores
// (fp32 float4, or bf16 hi/lo plane u16x4 with bias+relu fused).

template <bool BIAS, bool RELU, bool OUTPLANES, bool GUARD>
__global__ __launch_bounds__(256) void k_mm(MMArgs a, int M, int N, int K) {
  __shared__ __align__(16) char smem[67584];  // staging 64KB | f32 tile 128*132*4
  u16 (*lds)[4][4096] = (u16(*)[4][4096])smem;
  float* ct = (float*)smem;

  int z = blockIdx.z;
  int tid = threadIdx.x;
  int wv = tid >> 6, ln = tid & 63;
  int l15 = ln & 15, l4 = ln >> 4;
  int m0 = blockIdx.x * 128, n0 = blockIdx.y * 128;
  int wm = (wv & 1) * 64, wn = (wv >> 1) * 64;
  const u16* gb = (wv == 0) ? a.Ah[z] : (wv == 1) ? a.Al[z] : (wv == 2) ? a.Bh[z] : a.Bl[z];
  int row0 = (wv < 2) ? m0 : n0;

  f32x4 acc[4][4];
  f32x4 zz = {0.f, 0.f, 0.f, 0.f};
#pragma unroll
  for (int i = 0; i < 4; ++i)
#pragma unroll
    for (int j = 0; j < 4; ++j) acc[i][j] = zz;

  auto stage = [&](int d, int k0) {
#pragma unroll
    for (int it = 0; it < 8; ++it) {
      int slot = it * 64 + ln;
      int r = slot >> 2, c = slot & 3;
      int gc = c ^ ((r >> 2) & 3);
      gload_lds16(gb + ((size_t)(row0 + r) * K + k0 + gc * 8),
                  &lds[d][wv][it * 512]);
    }
  };

  auto compute = [&](int d) {
    bf16x8 ah[4], al[4], bh[4], bl[4];
#pragma unroll
    for (int i = 0; i < 4; ++i) {
      int r = wm + i * 16 + l15;
      int off = r * 32 + ((l4 ^ ((r >> 2) & 3)) << 3);
      ah[i] = *(const bf16x8*)&lds[d][0][off];
      al[i] = *(const bf16x8*)&lds[d][1][off];
    }
#pragma unroll
    for (int j = 0; j < 4; ++j) {
      int r = wn + j * 16 + l15;
      int off = r * 32 + ((l4 ^ ((r >> 2) & 3)) << 3);
      bh[j] = *(const bf16x8*)&lds[d][2][off];
      bl[j] = *(const bf16x8*)&lds[d][3][off];
    }
#pragma unroll
    for (int i = 0; i < 4; ++i)
#pragma unroll
      for (int j = 0; j < 4; ++j) {
        acc[i][j] = __builtin_amdgcn_mfma_f32_16x16x32_bf16(ah[i], bh[j], acc[i][j], 0, 0, 0);
        acc[i][j] = __builtin_amdgcn_mfma_f32_16x16x32_bf16(al[i], bh[j], acc[i][j], 0, 0, 0);
        acc[i][j] = __builtin_amdgcn_mfma_f32_16x16x32_bf16(ah[i], bl[j], acc[i][j], 0, 0, 0);
      }
  };

  stage(0, 0);
  __syncthreads();
  int nk = K >> 5;
  for (int t = 0; t < nk; ++t) {
    int cur = t & 1;
    if (t + 1 < nk) stage(cur ^ 1, (t + 1) << 5);
    compute(cur);
    __syncthreads();
  }

  // ---- epilogue: acc (D layout col=lane&15, row=4*(lane>>4)+reg) -> LDS ----
#pragma unroll
  for (int i = 0; i < 4; ++i)
#pragma unroll
    for (int rr = 0; rr < 4; ++rr) {
      int row = wm + i * 16 + l4 * 4 + rr;
#pragma unroll
      for (int j = 0; j < 4; ++j) {
        int col = wn + l15 + j * 16;
        ct[row * 132 + col] = acc[i][j][rr];
      }
    }
  __syncthreads();

  int tcol = (tid & 31) * 4;
  int trow = tid >> 5;
#pragma unroll
  for (int p = 0; p < 16; ++p) {
    int row = p * 8 + trow;
    int m = m0 + row;
    int n = n0 + tcol;
    if (GUARD && n >= N) continue;
    f32x4 v = *(f32x4*)&ct[row * 132 + tcol];
    float o[4];
#pragma unroll
    for (int e = 0; e < 4; ++e) {
      float x = v[e];
      if (BIAS) x += a.bias[z][n + e];
      if (RELU) x = fmaxf(x, 0.0f);
      o[e] = x;
    }
    if (OUTPLANES) {
      u16x4 hh, ll;
      if (m < M) {
#pragma unroll
        for (int e = 0; e < 4; ++e) {
          u16 h = f2bf(o[e]);
          hh[e] = h;
          ll[e] = f2bf(o[e] - bf2f(h));
        }
      } else {
#pragma unroll
        for (int e = 0; e < 4; ++e) { hh[e] = 0; ll[e] = 0; }
      }
      *(u16x4*)&a.Ch[z][(size_t)m * N + n] = hh;
      *(u16x4*)&a.Cl[z][(size_t)m * N + n] = ll;
    } else {
      if (m < M) {
        float4 o4 = {o[0], o[1], o[2], o[3]};
        *(float4*)&a.C[z][(size_t)m * N + n] = o4;
      }
    }
  }
}

// ---------------- sparse aggregation -> bf16 hi/lo planes ----------------

__global__ __launch_bounds__(128) void k_aggregate(AggArgs a) {
  int z = blockIdx.z;
  int c = blockIdx.x;
  int t = threadIdx.x;
  const float* XW = a.XW[z];
  const int* srcs = a.srcs[z];
  const float* normv = a.normv[z];
  int e0 = a.colptr[z][c], e1 = a.colptr[z][c + 1];
  float di = a.dinv[z][c];
  float sl = di * di;
  float4 v = ((const float4*)(XW + (size_t)c * FF))[t];
  float ax = v.x * sl, ay = v.y * sl, az = v.z * sl, aw = v.w * sl;
  int e = e0;
  for (; e + 1 < e1; e += 2) {
    int s0 = srcs[e], s1 = srcs[e + 1];
    float w0 = normv[e], w1 = normv[e + 1];
    float4 u0 = ((const float4*)(XW + (size_t)s0 * FF))[t];
    float4 u1 = ((const float4*)(XW + (size_t)s1 * FF))[t];
    ax = fmaf(w0, u0.x, ax); ay = fmaf(w0, u0.y, ay);
    az = fmaf(w0, u0.z, az); aw = fmaf(w0, u0.w, aw);
    ax = fmaf(w1, u1.x, ax); ay = fmaf(w1, u1.y, ay);
    az = fmaf(w1, u1.z, az); aw = fmaf(w1, u1.w, aw);
  }
  if (e < e1) {
    int s0 = srcs[e];
    float w0 = normv[e];
    float4 u0 = ((const float4*)(XW + (size_t)s0 * FF))[t];
    ax = fmaf(w0, u0.x, ax); ay = fmaf(w0, u0.y, ay);
    az = fmaf(w0, u0.z, az); aw = fmaf(w0, u0.w, aw);
  }
  float4 b4 = ((const float4*)a.bias[z])[t];
  float o[4];
  o[0] = fmaxf(ax + b4.x, 0.0f);
  o[1] = fmaxf(ay + b4.y, 0.0f);
  o[2] = fmaxf(az + b4.z, 0.0f);
  o[3] = fmaxf(aw + b4.w, 0.0f);
  u16x4 hh, ll;
#pragma unroll
  for (int q = 0; q < 4; ++q) {
    u16 h = f2bf(o[q]);
    hh[q] = h;
    ll[q] = f2bf(o[q] - bf2f(h));
  }
  *(u16x4*)&a.Hh[z][(size_t)c * FF + 4 * t] = hh;
  *(u16x4*)&a.Hl[z][(size_t)c * FF + 4 * t] = ll;
}

// ---------------- host orchestration ----------------

extern "C" void kernel_launch(void* const* d_in, const int* in_sizes, int n_in,
                              void* d_out, int out_size, void* d_ws, size_t ws_size,
                              hipStream_t stream) {
  const float* x_m    = (const float*)d_in[0];
  const float* x_d    = (const float*)d_in[1];
  const float* data_m = (const float*)d_in[2];
  const float* data_d = (const float*)d_in[3];
  const int*   ei_m   = (const int*)d_in[4];
  const int*   ei_d   = (const int*)d_in[5];
  const float* Wg1 = (const float*)d_in[6];
  const float* bg1 = (const float*)d_in[7];
  const float* Wg2 = (const float*)d_in[8];
  const float* bg2 = (const float*)d_in[9];
  const float* Wd1 = (const float*)d_in[10];
  const float* bd1 = (const float*)d_in[11];
  const float* Wd2 = (const float*)d_in[12];
  const float* bd2 = (const float*)d_in[13];
  const float* lx1_w = (const float*)d_in[14];
  const float* lx1_b = (const float*)d_in[15];
  const float* lx2_w = (const float*)d_in[16];
  const float* lx2_b = (const float*)d_in[17];
  const float* lx3_w = (const float*)d_in[18];
  const float* lx3_b = (const float*)d_in[19];
  const float* ly1_w = (const float*)d_in[20];
  const float* ly1_b = (const float*)d_in[21];
  const float* ly2_w = (const float*)d_in[22];
  const float* ly2_b = (const float*)d_in[23];
  const float* ly3_w = (const float*)d_in[24];
  const float* ly3_b = (const float*)d_in[25];
  float* out = (float*)d_out;

  char* base = (char*)d_ws;
  size_t off = 0;
  auto alloc = [&](size_t bytes) -> char* {
    char* p = base + off;
    off += (bytes + 255) & ~(size_t)255;
    return p;
  };
  // activation planes (x planes reused as h planes after GCN1)
  u16* hh[2], *hl[2];
  for (int z = 0; z < 2; ++z) {
    hh[z] = (u16*)alloc((size_t)MP * FF * 2);
    hl[z] = (u16*)alloc((size_t)MP * FF * 2);
  }
  u16* p1h[2], *p1l[2], *p2h[2], *p2l[2], *fh[2], *fl[2];
  for (int z = 0; z < 2; ++z) {
    p1h[z] = (u16*)alloc((size_t)MP * 256 * 2);
    p1l[z] = (u16*)alloc((size_t)MP * 256 * 2);
    p2h[z] = (u16*)alloc((size_t)MP * 128 * 2);
    p2l[z] = (u16*)alloc((size_t)MP * 128 * 2);
    fh[z]  = (u16*)alloc((size_t)MP * 64 * 2);
    fl[z]  = (u16*)alloc((size_t)MP * 64 * 2);
  }
  float* bufA[2];
  for (int z = 0; z < 2; ++z) bufA[z] = (float*)alloc((size_t)NN * FF * 4);
  u16* wth[2], *wtl[2];
  for (int z = 0; z < 2; ++z) {
    wth[z] = (u16*)alloc((size_t)FF * FF * 2);
    wtl[z] = (u16*)alloc((size_t)FF * FF * 2);
  }
  PreArgs P;
  for (int z = 0; z < 2; ++z) {
    P.data[z]   = z ? data_d : data_m;
    P.ei[z]     = z ? ei_d : ei_m;
    P.wbuf[z]   = (float*)alloc((size_t)NE * 4);
    P.normv[z]  = (float*)alloc((size_t)NE * 4);
    P.srcs[z]   = (int*)alloc((size_t)NE * 4);
    P.deg[z]    = (float*)alloc((size_t)NN * 4);
    P.dinv[z]   = (float*)alloc((size_t)NN * 4);
    P.cnt[z]    = (int*)alloc((size_t)NN * 4);
    P.colptr[z] = (int*)alloc((size_t)(NN + 1) * 4);
  }

  int nb = (NN + 255) / 256;
  int eb = (NE + 255) / 256;
  k_init<<<dim3(nb, 1, 2), 256, 0, stream>>>(P, NN);
  k_edge_w<<<dim3(eb, 1, 2), 256, 0, stream>>>(P, NE, NN);
  k_dinv<<<dim3(nb, 1, 2), 256, 0, stream>>>(P, NN);
  k_scan<<<dim3(1, 1, 2), 256, 0, stream>>>(P, NN);
  k_scatter<<<dim3(eb, 1, 2), 256, 0, stream>>>(P, NE);

  // split input activations into x planes (aliased with h planes)
  SplitArgs SA;
  SA.x[0] = x_m; SA.x[1] = x_d;
  for (int z = 0; z < 2; ++z) { SA.ph[z] = hh[z]; SA.pl[z] = hl[z]; }
  int sb = (MP * FF / 4 + 255) / 256;
  k_split_act<<<dim3(sb, 1, 2), 256, 0, stream>>>(SA, NN * FF, MP * FF);

  auto splitW = [&](const float* Wm, const float* Wd, int K, int N) {
    WTArgs WA;
    WA.W[0] = Wm; WA.W[1] = Wd;
    for (int z = 0; z < 2; ++z) { WA.Th[z] = wth[z]; WA.Tl[z] = wtl[z]; }
    k_split_wT<<<dim3(N / 32, K / 32, 2), 256, 0, stream>>>(WA, K, N);
  };

  MMArgs MA;
  for (int z = 0; z < 2; ++z) {
    MA.Bh[z] = wth[z]; MA.Bl[z] = wtl[z];
    MA.bias[z] = nullptr; MA.C[z] = nullptr; MA.Ch[z] = nullptr; MA.Cl[z] = nullptr;
  }

  AggArgs GA;
  for (int z = 0; z < 2; ++z) {
    GA.XW[z] = bufA[z];
    GA.colptr[z] = P.colptr[z];
    GA.srcs[z] = P.srcs[z];
    GA.normv[z] = P.normv[z];
    GA.dinv[z] = P.dinv[z];
    GA.Hh[z] = hh[z]; GA.Hl[z] = hl[z];
  }

  // ---- GCN layer 1 ----
  splitW(Wg1, Wd1, FF, FF);
  for (int z = 0; z < 2; ++z) {
    MA.Ah[z] = hh[z]; MA.Al[z] = hl[z]; MA.C[z] = bufA[z];
  }
  k_mm<false, false, false, false><<<dim3(63, FF / 128, 2), 256, 0, stream>>>(MA, NN, FF, FF);
  GA.bias[0] = bg1; GA.bias[1] = bd1;
  k_aggregate<<<dim3(NN, 1, 2), 128, 0, stream>>>(GA);

  // ---- GCN layer 2 ----
  splitW(Wg2, Wd2, FF, FF);
  k_mm<false, false, false, false><<<dim3(63, FF / 128, 2), 256, 0, stream>>>(MA, NN, FF, FF);
  GA.bias[0] = bg2; GA.bias[1] = bd2;
  k_aggregate<<<dim3(NN, 1, 2), 128, 0, stream>>>(GA);

  // ---- MLP1: 512 -> 256, planes out ----
  splitW(lx1_w, ly1_w, FF, 256);
  MA.bias[0] = lx1_b; MA.bias[1] = ly1_b;
  for (int z = 0; z < 2; ++z) { MA.Ch[z] = p1h[z]; MA.Cl[z] = p1l[z]; }
  k_mm<true, true, true, false><<<dim3(63, 2, 2), 256, 0, stream>>>(MA, NN, 256, FF);

  // ---- MLP2: 256 -> 128 ----
  splitW(lx2_w, ly2_w, 256, 128);
  MA.bias[0] = lx2_b; MA.bias[1] = ly2_b;
  for (int z = 0; z < 2; ++z) {
    MA.Ah[z] = p1h[z]; MA.Al[z] = p1l[z];
    MA.Ch[z] = p2h[z]; MA.Cl[z] = p2l[z];
  }
  k_mm<true, true, true, false><<<dim3(63, 1, 2), 256, 0, stream>>>(MA, NN, 128, 256);

  // ---- MLP3: 128 -> 64 (tile N-guard) ----
  splitW(lx3_w, ly3_w, 128, 64);
  MA.bias[0] = lx3_b; MA.bias[1] = ly3_b;
  for (int z = 0; z < 2; ++z) {
    MA.Ah[z] = p2h[z]; MA.Al[z] = p2l[z];
    MA.Ch[z] = fh[z]; MA.Cl[z] = fl[z];
  }
  k_mm<true, true, true, true><<<dim3(63, 1, 2), 256, 0, stream>>>(MA, NN, 64, 128);

  // ---- scores = x @ y^T ----
  MMArgs SC;
  SC.Ah[0] = fh[0]; SC.Al[0] = fl[0];
  SC.Bh[0] = fh[1]; SC.Bl[0] = fl[1];
  SC.Ah[1] = SC.Ah[0]; SC.Al[1] = SC.Al[0]; SC.Bh[1] = SC.Bh[0]; SC.Bl[1] = SC.Bl[0];
  SC.bias[0] = nullptr; SC.bias[1] = nullptr;
  SC.C[0] = out; SC.C[1] = out;
  SC.Ch[0] = SC.Ch[1] = nullptr; SC.Cl[0] = SC.Cl[1] = nullptr;
  k_mm<false, false, false, true><<<dim3(63, 63, 1), 256, 0, stream>>>(SC, NN, NN, 64);
}

// Round 5
// 466.938 us; speedup vs baseline: 1.9447x; 1.2388x over previous
//
#include <hip/hip_runtime.h>

typedef unsigned short u16;
typedef unsigned int u32;
typedef __attribute__((ext_vector_type(8))) short bf16x8;
typedef __attribute__((ext_vector_type(4))) float f32x4;
typedef __attribute__((ext_vector_type(4))) unsigned short u16x4;
typedef __attribute__((ext_vector_type(2))) unsigned short u16x2;

static const int NN = 8000;    // nodes per graph (M == D)
static const int NE = 256000;  // edges per graph
static const int FF = 512;     // feature dim
static const int MP = 8064;    // 63 * 128 padded rows

__device__ __forceinline__ u16 f2bf(float x) {
  union { float f; u32 u; } a; a.f = x;
  u32 r = a.u + 0x7FFF + ((a.u >> 16) & 1);  // RNE
  return (u16)(r >> 16);
}
__device__ __forceinline__ float bf2f(u16 b) {
  union { float f; u32 u; } a; a.u = ((u32)b) << 16;
  return a.f;
}

__device__ __forceinline__ void gload_lds16(const void* g, void* l) {
  __builtin_amdgcn_global_load_lds(
      (const __attribute__((address_space(1))) unsigned int*)g,
      (__attribute__((address_space(3))) unsigned int*)l, 16, 0, 0);
}

// ---------------- batched arg structs (blockIdx.z = graph) ----------------

struct PreArgs {
  const float* data[2];
  const int* ei[2];
  float* wbuf[2];
  float* deg[2];
  int* cnt[2];
  float* dinv[2];
  int* colptr[2];
  int2* edata[2];  // packed (src, norm-bits)
};

struct SplitArgs {
  const float* x[2];
  u16* ph[2];
  u16* pl[2];
};

struct WTArgs {
  const float* W[2];
  u16* Th[2];
  u16* Tl[2];
};

struct MMArgs {
  const u16* Ah[2]; const u16* Al[2];
  const u16* Bh[2]; const u16* Bl[2];
  const float* bias[2];
  float* C[2];          // fp32 output (when !OUTPLANES)
  u16* Ch[2]; u16* Cl[2];  // plane outputs (when OUTPLANES)
};

struct AggArgs {
  const float* XW[2];
  const int* colptr[2];
  const int2* edata[2];
  const float* dinv[2];
  const float* bias[2];
  u16* Hh[2];
  u16* Hl[2];
};

// ---------------- graph preprocessing ----------------

__global__ __launch_bounds__(256) void k_init(PreArgs p, int n) {
  int z = blockIdx.z;
  int i = blockIdx.x * 256 + threadIdx.x;
  if (i < n) { p.deg[z][i] = 1.0f; p.cnt[z][i] = 0; }
}

__global__ __launch_bounds__(256) void k_edge_w(PreArgs p, int E, int n) {
  int z = blockIdx.z;
  int e = blockIdx.x * 256 + threadIdx.x;
  if (e >= E) return;
  const int* ei = p.ei[z];
  int r = ei[e];
  int c = ei[E + e];
  float w = fmaxf(p.data[z][(size_t)r * n + c], 0.0f);
  p.wbuf[z][e] = w;
  atomicAdd(&p.deg[z][c], w);
  atomicAdd(&p.cnt[z][c], 1);
}

__global__ __launch_bounds__(256) void k_dinv(PreArgs p, int n) {
  int z = blockIdx.z;
  int i = blockIdx.x * 256 + threadIdx.x;
  if (i < n) p.dinv[z][i] = 1.0f / sqrtf(p.deg[z][i]);
}

// one block per z: exclusive scan of cnt -> colptr; zero cnt
__global__ __launch_bounds__(256) void k_scan(PreArgs p, int n) {
  int z = blockIdx.z;
  const int* cnt = p.cnt[z];
  int* colptr = p.colptr[z];
  int* cntz = p.cnt[z];
  __shared__ int part[256];
  int t = threadIdx.x;
  const int CH = 32;
  int base = t * CH;
  int local[CH];
  int s = 0;
  for (int i = 0; i < CH; ++i) {
    int idx = base + i;
    int v = (idx < n) ? cnt[idx] : 0;
    local[i] = s;
    s += v;
  }
  part[t] = s;
  __syncthreads();
  for (int o = 1; o < 256; o <<= 1) {
    int v = (t >= o) ? part[t - o] : 0;
    __syncthreads();
    part[t] += v;
    __syncthreads();
  }
  int pre = (t == 0) ? 0 : part[t - 1];
  for (int i = 0; i < CH; ++i) {
    int idx = base + i;
    if (idx < n) { colptr[idx] = pre + local[i]; cntz[idx] = 0; }
  }
  if (t == 255) colptr[n] = part[255];
}

__global__ __launch_bounds__(256) void k_scatter(PreArgs p, int E) {
  int z = blockIdx.z;
  int e = blockIdx.x * 256 + threadIdx.x;
  if (e >= E) return;
  const int* ei = p.ei[z];
  int r = ei[e], c = ei[E + e];
  int pos = p.colptr[z][c] + atomicAdd(&p.cnt[z][c], 1);
  int2 sn;
  sn.x = r;
  sn.y = __float_as_int(p.dinv[z][r] * p.wbuf[z][e] * p.dinv[z][c]);
  p.edata[z][pos] = sn;
}

// ---------------- fp32 -> bf16 hi/lo split (activations, zero-padded) ------

__global__ __launch_bounds__(256) void k_split_act(SplitArgs a, int tot_in, int tot_pad) {
  int z = blockIdx.z;
  int i = (blockIdx.x * 256 + threadIdx.x) * 4;
  if (i >= tot_pad) return;
  float4 v = (i < tot_in) ? *(const float4*)&a.x[z][i] : make_float4(0.f, 0.f, 0.f, 0.f);
  u16x4 h, l;
#pragma unroll
  for (int e = 0; e < 4; ++e) {
    float x = (&v.x)[e];
    u16 hh = f2bf(x);
    h[e] = hh;
    l[e] = f2bf(x - bf2f(hh));
  }
  *(u16x4*)&a.ph[z][i] = h;
  *(u16x4*)&a.pl[z][i] = l;
}

// weight transpose + split: W [K][N] -> Th/Tl [N][K]
__global__ __launch_bounds__(256) void k_split_wT(WTArgs a, int K, int N) {
  int z = blockIdx.z;
  __shared__ float tile[32][33];
  int tx = threadIdx.x & 31, ty = threadIdx.x >> 5;
  int n0 = blockIdx.x * 32, k0 = blockIdx.y * 32;
#pragma unroll
  for (int r = 0; r < 32; r += 8)
    tile[r + ty][tx] = a.W[z][(size_t)(k0 + r + ty) * N + n0 + tx];
  __syncthreads();
#pragma unroll
  for (int r = 0; r < 32; r += 8) {
    float v = tile[tx][r + ty];
    int n = n0 + r + ty, k = k0 + tx;
    u16 h = f2bf(v);
    a.Th[z][(size_t)n * K + k] = h;
    a.Tl[z][(size_t)n * K + k] = f2bf(v - bf2f(h));
  }
}

// ---------------- bf16x3 MFMA GEMM ----------------
// C[M x N] = A[M x K] @ B[K x N]; A planes [Mp][K], B planes (transposed)
// [Np][K]. 128x128 tile, BK=32, 4 waves, double-buffered global_load_lds
// staging with chunk-XOR swizzle, 3 MFMA per fragment (hh + lh + hl).
// Epilogue: acc -> LDS f32 tile (stride 132) -> coalesced stores.

template <bool BIAS, bool RELU, bool OUTPLANES, bool GUARD, bool NT>
__global__ __launch_bounds__(256) void k_mm(MMArgs a, int M, int N, int K) {
  __shared__ __align__(16) char smem[67584];  // staging 64KB | f32 tile 128*132*4
  u16 (*lds)[4][4096] = (u16(*)[4][4096])smem;
  float* ct = (float*)smem;

  int z = blockIdx.z;
  int tid = threadIdx.x;
  int wv = tid >> 6, ln = tid & 63;
  int l15 = ln & 15, l4 = ln >> 4;
  int m0 = blockIdx.x * 128, n0 = blockIdx.y * 128;
  int wm = (wv & 1) * 64, wn = (wv >> 1) * 64;
  const u16* gb = (wv == 0) ? a.Ah[z] : (wv == 1) ? a.Al[z] : (wv == 2) ? a.Bh[z] : a.Bl[z];
  int row0 = (wv < 2) ? m0 : n0;

  f32x4 acc[4][4];
  f32x4 zz = {0.f, 0.f, 0.f, 0.f};
#pragma unroll
  for (int i = 0; i < 4; ++i)
#pragma unroll
    for (int j = 0; j < 4; ++j) acc[i][j] = zz;

  auto stage = [&](int d, int k0) {
#pragma unroll
    for (int it = 0; it < 8; ++it) {
      int slot = it * 64 + ln;
      int r = slot >> 2, c = slot & 3;
      int gc = c ^ ((r >> 2) & 3);
      gload_lds16(gb + ((size_t)(row0 + r) * K + k0 + gc * 8),
                  &lds[d][wv][it * 512]);
    }
  };

  auto compute = [&](int d) {
    bf16x8 ah[4], al[4], bh[4], bl[4];
#pragma unroll
    for (int i = 0; i < 4; ++i) {
      int r = wm + i * 16 + l15;
      int off = r * 32 + ((l4 ^ ((r >> 2) & 3)) << 3);
      ah[i] = *(const bf16x8*)&lds[d][0][off];
      al[i] = *(const bf16x8*)&lds[d][1][off];
    }
#pragma unroll
    for (int j = 0; j < 4; ++j) {
      int r = wn + j * 16 + l15;
      int off = r * 32 + ((l4 ^ ((r >> 2) & 3)) << 3);
      bh[j] = *(const bf16x8*)&lds[d][2][off];
      bl[j] = *(const bf16x8*)&lds[d][3][off];
    }
#pragma unroll
    for (int i = 0; i < 4; ++i)
#pragma unroll
      for (int j = 0; j < 4; ++j) {
        acc[i][j] = __builtin_amdgcn_mfma_f32_16x16x32_bf16(ah[i], bh[j], acc[i][j], 0, 0, 0);
        acc[i][j] = __builtin_amdgcn_mfma_f32_16x16x32_bf16(al[i], bh[j], acc[i][j], 0, 0, 0);
        acc[i][j] = __builtin_amdgcn_mfma_f32_16x16x32_bf16(ah[i], bl[j], acc[i][j], 0, 0, 0);
      }
  };

  stage(0, 0);
  __syncthreads();
  int nk = K >> 5;
  for (int t = 0; t < nk; ++t) {
    int cur = t & 1;
    if (t + 1 < nk) stage(cur ^ 1, (t + 1) << 5);
    compute(cur);
    __syncthreads();
  }

  // ---- epilogue: acc (D layout col=lane&15, row=4*(lane>>4)+reg) -> LDS ----
#pragma unroll
  for (int i = 0; i < 4; ++i)
#pragma unroll
    for (int rr = 0; rr < 4; ++rr) {
      int row = wm + i * 16 + l4 * 4 + rr;
#pragma unroll
      for (int j = 0; j < 4; ++j) {
        int col = wn + l15 + j * 16;
        ct[row * 132 + col] = acc[i][j][rr];
      }
    }
  __syncthreads();

  int tcol = (tid & 31) * 4;
  int trow = tid >> 5;
#pragma unroll
  for (int p = 0; p < 16; ++p) {
    int row = p * 8 + trow;
    int m = m0 + row;
    int n = n0 + tcol;
    if (GUARD && n >= N) continue;
    f32x4 v = *(f32x4*)&ct[row * 132 + tcol];
    float o[4];
#pragma unroll
    for (int e = 0; e < 4; ++e) {
      float x = v[e];
      if (BIAS) x += a.bias[z][n + e];
      if (RELU) x = fmaxf(x, 0.0f);
      o[e] = x;
    }
    if (OUTPLANES) {
      u16x4 hh, ll;
      if (m < M) {
#pragma unroll
        for (int e = 0; e < 4; ++e) {
          u16 h = f2bf(o[e]);
          hh[e] = h;
          ll[e] = f2bf(o[e] - bf2f(h));
        }
      } else {
#pragma unroll
        for (int e = 0; e < 4; ++e) { hh[e] = 0; ll[e] = 0; }
      }
      *(u16x4*)&a.Ch[z][(size_t)m * N + n] = hh;
      *(u16x4*)&a.Cl[z][(size_t)m * N + n] = ll;
    } else {
      if (m < M) {
        f32x4 o4 = {o[0], o[1], o[2], o[3]};
        if (NT)
          __builtin_nontemporal_store(o4, (f32x4*)&a.C[z][(size_t)m * N + n]);
        else
          *(f32x4*)&a.C[z][(size_t)m * N + n] = o4;
      }
    }
  }
}

// ---------------- sparse aggregation (XCD-chunked) -> bf16 hi/lo planes ----
// Feature dim split into 4 chunks of 128 floats. chunk = (blockIdx%8)&3 so,
// with round-robin workgroup->XCD dispatch, each XCD touches one 4 MB slab
// of XW that fits its private L2. Block = 1 wave (64 thr), float2 per lane.

__global__ __launch_bounds__(64) void k_aggregate(AggArgs a) {
  int z = blockIdx.z;
  int gid = blockIdx.x;          // 0..31999
  int q = gid >> 3, r = gid & 7;
  int chunk = r & 3;             // pinned to XCDs {chunk, chunk+4}
  int c = q * 2 + (r >> 2);      // node 0..7999
  int t = threadIdx.x;           // 0..63
  int fo = chunk * 128 + t * 2;
  const float* XW = a.XW[z];
  const int2* ed = a.edata[z];
  int e0 = a.colptr[z][c], e1 = a.colptr[z][c + 1];
  float di = a.dinv[z][c];
  float sl = di * di;
  float2 v = *(const float2*)&XW[(size_t)c * FF + fo];
  float ax = v.x * sl, ay = v.y * sl;
  int e = e0;
  for (; e + 1 < e1; e += 2) {
    int2 d0 = ed[e], d1 = ed[e + 1];
    float2 u0 = *(const float2*)&XW[(size_t)d0.x * FF + fo];
    float2 u1 = *(const float2*)&XW[(size_t)d1.x * FF + fo];
    float w0 = __int_as_float(d0.y), w1 = __int_as_float(d1.y);
    ax = fmaf(w0, u0.x, ax); ay = fmaf(w0, u0.y, ay);
    ax = fmaf(w1, u1.x, ax); ay = fmaf(w1, u1.y, ay);
  }
  if (e < e1) {
    int2 d0 = ed[e];
    float2 u0 = *(const float2*)&XW[(size_t)d0.x * FF + fo];
    float w0 = __int_as_float(d0.y);
    ax = fmaf(w0, u0.x, ax); ay = fmaf(w0, u0.y, ay);
  }
  float2 b2 = *(const float2*)&a.bias[z][fo];
  float o0 = fmaxf(ax + b2.x, 0.0f);
  float o1 = fmaxf(ay + b2.y, 0.0f);
  u16 h0 = f2bf(o0), h1 = f2bf(o1);
  u16x2 hh = {h0, h1};
  u16x2 ll = {f2bf(o0 - bf2f(h0)), f2bf(o1 - bf2f(h1))};
  *(u16x2*)&a.Hh[z][(size_t)c * FF + fo] = hh;
  *(u16x2*)&a.Hl[z][(size_t)c * FF + fo] = ll;
}

// ---------------- host orchestration ----------------

extern "C" void kernel_launch(void* const* d_in, const int* in_sizes, int n_in,
                              void* d_out, int out_size, void* d_ws, size_t ws_size,
                              hipStream_t stream) {
  const float* x_m    = (const float*)d_in[0];
  const float* x_d    = (const float*)d_in[1];
  const float* data_m = (const float*)d_in[2];
  const float* data_d = (const float*)d_in[3];
  const int*   ei_m   = (const int*)d_in[4];
  const int*   ei_d   = (const int*)d_in[5];
  const float* Wg1 = (const float*)d_in[6];
  const float* bg1 = (const float*)d_in[7];
  const float* Wg2 = (const float*)d_in[8];
  const float* bg2 = (const float*)d_in[9];
  const float* Wd1 = (const float*)d_in[10];
  const float* bd1 = (const float*)d_in[11];
  const float* Wd2 = (const float*)d_in[12];
  const float* bd2 = (const float*)d_in[13];
  const float* lx1_w = (const float*)d_in[14];
  const float* lx1_b = (const float*)d_in[15];
  const float* lx2_w = (const float*)d_in[16];
  const float* lx2_b = (const float*)d_in[17];
  const float* lx3_w = (const float*)d_in[18];
  const float* lx3_b = (const float*)d_in[19];
  const float* ly1_w = (const float*)d_in[20];
  const float* ly1_b = (const float*)d_in[21];
  const float* ly2_w = (const float*)d_in[22];
  const float* ly2_b = (const float*)d_in[23];
  const float* ly3_w = (const float*)d_in[24];
  const float* ly3_b = (const float*)d_in[25];
  float* out = (float*)d_out;

  char* base = (char*)d_ws;
  size_t off = 0;
  auto alloc = [&](size_t bytes) -> char* {
    char* p = base + off;
    off += (bytes + 255) & ~(size_t)255;
    return p;
  };
  u16* hh[2], *hl[2];
  for (int z = 0; z < 2; ++z) {
    hh[z] = (u16*)alloc((size_t)MP * FF * 2);
    hl[z] = (u16*)alloc((size_t)MP * FF * 2);
  }
  u16* p1h[2], *p1l[2], *p2h[2], *p2l[2], *fh[2], *fl[2];
  for (int z = 0; z < 2; ++z) {
    p1h[z] = (u16*)alloc((size_t)MP * 256 * 2);
    p1l[z] = (u16*)alloc((size_t)MP * 256 * 2);
    p2h[z] = (u16*)alloc((size_t)MP * 128 * 2);
    p2l[z] = (u16*)alloc((size_t)MP * 128 * 2);
    fh[z]  = (u16*)alloc((size_t)MP * 64 * 2);
    fl[z]  = (u16*)alloc((size_t)MP * 64 * 2);
  }
  float* bufA[2];
  for (int z = 0; z < 2; ++z) bufA[z] = (float*)alloc((size_t)NN * FF * 4);
  u16* wth[2], *wtl[2];
  for (int z = 0; z < 2; ++z) {
    wth[z] = (u16*)alloc((size_t)FF * FF * 2);
    wtl[z] = (u16*)alloc((size_t)FF * FF * 2);
  }
  PreArgs P;
  for (int z = 0; z < 2; ++z) {
    P.data[z]   = z ? data_d : data_m;
    P.ei[z]     = z ? ei_d : ei_m;
    P.wbuf[z]   = (float*)alloc((size_t)NE * 4);
    P.edata[z]  = (int2*)alloc((size_t)NE * 8);
    P.deg[z]    = (float*)alloc((size_t)NN * 4);
    P.dinv[z]   = (float*)alloc((size_t)NN * 4);
    P.cnt[z]    = (int*)alloc((size_t)NN * 4);
    P.colptr[z] = (int*)alloc((size_t)(NN + 1) * 4);
  }

  int nb = (NN + 255) / 256;
  int eb = (NE + 255) / 256;
  k_init<<<dim3(nb, 1, 2), 256, 0, stream>>>(P, NN);
  k_edge_w<<<dim3(eb, 1, 2), 256, 0, stream>>>(P, NE, NN);
  k_dinv<<<dim3(nb, 1, 2), 256, 0, stream>>>(P, NN);
  k_scan<<<dim3(1, 1, 2), 256, 0, stream>>>(P, NN);
  k_scatter<<<dim3(eb, 1, 2), 256, 0, stream>>>(P, NE);

  SplitArgs SA;
  SA.x[0] = x_m; SA.x[1] = x_d;
  for (int z = 0; z < 2; ++z) { SA.ph[z] = hh[z]; SA.pl[z] = hl[z]; }
  int sb = (MP * FF / 4 + 255) / 256;
  k_split_act<<<dim3(sb, 1, 2), 256, 0, stream>>>(SA, NN * FF, MP * FF);

  auto splitW = [&](const float* Wm, const float* Wd, int K, int N) {
    WTArgs WA;
    WA.W[0] = Wm; WA.W[1] = Wd;
    for (int z = 0; z < 2; ++z) { WA.Th[z] = wth[z]; WA.Tl[z] = wtl[z]; }
    k_split_wT<<<dim3(N / 32, K / 32, 2), 256, 0, stream>>>(WA, K, N);
  };

  MMArgs MA;
  for (int z = 0; z < 2; ++z) {
    MA.Bh[z] = wth[z]; MA.Bl[z] = wtl[z];
    MA.bias[z] = nullptr; MA.C[z] = nullptr; MA.Ch[z] = nullptr; MA.Cl[z] = nullptr;
  }

  AggArgs GA;
  for (int z = 0; z < 2; ++z) {
    GA.XW[z] = bufA[z];
    GA.colptr[z] = P.colptr[z];
    GA.edata[z] = P.edata[z];
    GA.dinv[z] = P.dinv[z];
    GA.Hh[z] = hh[z]; GA.Hl[z] = hl[z];
  }

  // ---- GCN layer 1 ----
  splitW(Wg1, Wd1, FF, FF);
  for (int z = 0; z < 2; ++z) {
    MA.Ah[z] = hh[z]; MA.Al[z] = hl[z]; MA.C[z] = bufA[z];
  }
  k_mm<false, false, false, false, false><<<dim3(63, FF / 128, 2), 256, 0, stream>>>(MA, NN, FF, FF);
  GA.bias[0] = bg1; GA.bias[1] = bd1;
  k_aggregate<<<dim3(32000, 1, 2), 64, 0, stream>>>(GA);

  // ---- GCN layer 2 ----
  splitW(Wg2, Wd2, FF, FF);
  k_mm<false, false, false, false, false><<<dim3(63, FF / 128, 2), 256, 0, stream>>>(MA, NN, FF, FF);
  GA.bias[0] = bg2; GA.bias[1] = bd2;
  k_aggregate<<<dim3(32000, 1, 2), 64, 0, stream>>>(GA);

  // ---- MLP1: 512 -> 256, planes out ----
  splitW(lx1_w, ly1_w, FF, 256);
  MA.bias[0] = lx1_b; MA.bias[1] = ly1_b;
  for (int z = 0; z < 2; ++z) { MA.Ch[z] = p1h[z]; MA.Cl[z] = p1l[z]; }
  k_mm<true, true, true, false, false><<<dim3(63, 2, 2), 256, 0, stream>>>(MA, NN, 256, FF);

  // ---- MLP2: 256 -> 128 ----
  splitW(lx2_w, ly2_w, 256, 128);
  MA.bias[0] = lx2_b; MA.bias[1] = ly2_b;
  for (int z = 0; z < 2; ++z) {
    MA.Ah[z] = p1h[z]; MA.Al[z] = p1l[z];
    MA.Ch[z] = p2h[z]; MA.Cl[z] = p2l[z];
  }
  k_mm<true, true, true, false, false><<<dim3(63, 1, 2), 256, 0, stream>>>(MA, NN, 128, 256);

  // ---- MLP3: 128 -> 64 (tile N-guard) ----
  splitW(lx3_w, ly3_w, 128, 64);
  MA.bias[0] = lx3_b; MA.bias[1] = ly3_b;
  for (int z = 0; z < 2; ++z) {
    MA.Ah[z] = p2h[z]; MA.Al[z] = p2l[z];
    MA.Ch[z] = fh[z]; MA.Cl[z] = fl[z];
  }
  k_mm<true, true, true, true, false><<<dim3(63, 1, 2), 256, 0, stream>>>(MA, NN, 64, 128);

  // ---- scores = x @ y^T (nontemporal 256 MB write) ----
  MMArgs SC;
  SC.Ah[0] = fh[0]; SC.Al[0] = fl[0];
  SC.Bh[0] = fh[1]; SC.Bl[0] = fl[1];
  SC.Ah[1] = SC.Ah[0]; SC.Al[1] = SC.Al[0]; SC.Bh[1] = SC.Bh[0]; SC.Bl[1] = SC.Bl[0];
  SC.bias[0] = nullptr; SC.bias[1] = nullptr;
  SC.C[0] = out; SC.C[1] = out;
  SC.Ch[0] = SC.Ch[1] = nullptr; SC.Cl[0] = SC.Cl[1] = nullptr;
  k_mm<false, false, false, true, true><<<dim3(63, 63, 1), 256, 0, stream>>>(SC, NN, NN, 64);
}